// Round 5
// baseline (304.221 us; speedup 1.0000x reference)
//
#include <hip/hip_runtime.h>

#define B_ 2
#define L_ 4096
#define D_ 256
#define W_ 128

typedef __bf16 bf16;
typedef __bf16 bf16x8 __attribute__((ext_vector_type(8)));
typedef __bf16 bf16x4 __attribute__((ext_vector_type(4)));
typedef float f32x4 __attribute__((ext_vector_type(4)));

#define MFMA16(a, b, c) __builtin_amdgcn_mfma_f32_16x16x32_bf16((a), (b), (c), 0, 0, 0)

__device__ __forceinline__ int imin(int a, int b) { return a < b ? a : b; }
__device__ __forceinline__ int imax(int a, int b) { return a > b ? a : b; }

// Split 8 consecutive f32 into hi/lo bf16 fragments (hi = rn(x), lo = rn(x-hi)).
__device__ __forceinline__ void split8(const float* p, bf16x8& hi, bf16x8& lo) {
  f32x4 v0 = ((const f32x4*)p)[0], v1 = ((const f32x4*)p)[1];
#pragma unroll
  for (int j = 0; j < 4; ++j) {
    bf16 h0 = (bf16)v0[j]; hi[j] = h0; lo[j] = (bf16)(v0[j] - (float)h0);
    bf16 h1 = (bf16)v1[j]; hi[j + 4] = h1; lo[j + 4] = (bf16)(v1[j] - (float)h1);
  }
}

// Convert 8 consecutive f32 to bf16x8 (single rounding).
__device__ __forceinline__ bf16x8 cvt8(const float* p) {
  f32x4 v0 = ((const f32x4*)p)[0], v1 = ((const f32x4*)p)[1];
  bf16x8 r;
#pragma unroll
  for (int j = 0; j < 4; ++j) { r[j] = (bf16)v0[j]; r[j + 4] = (bf16)v1[j]; }
  return r;
}

// ---------------------------------------------------------------------------
// Wc = Wv @ Wo (f32 exact), bc = bv @ Wo + bo.  grid 256 blocks x 256 thr.
// out = P @ (value @ Wc + bc) == ((P@v)@Wo + bo) since softmax rows sum to 1.
// ---------------------------------------------------------------------------
__global__ void make_wc(const float* __restrict__ Wv, const float* __restrict__ Wo,
                        const float* __restrict__ bv, const float* __restrict__ bo,
                        float* __restrict__ Wc, float* __restrict__ bc) {
  int i = blockIdx.x, j = threadIdx.x;
  float s = 0.f;
  for (int k = 0; k < 256; ++k) s = fmaf(Wv[i * 256 + k], Wo[k * 256 + j], s);
  Wc[i * 256 + j] = s;
  if (i == 0) {
    float t = 0.f;
    for (int k = 0; k < 256; ++k) t = fmaf(bv[k], Wo[k * 256 + j], t);
    bc[j] = t + bo[j];
  }
}

// ---------------------------------------------------------------------------
// Transpose f32 256x256 matrices -> split bf16 WThi[n][k], WTlo[n][k].
// grid (8,8,3): z=0 Wq, z=1 Wk, z=2 Wc. block 256.
// ---------------------------------------------------------------------------
__global__ void prep_weights(const float* __restrict__ Wq, const float* __restrict__ Wk,
                             const float* __restrict__ Wc,
                             bf16* __restrict__ hi0, bf16* __restrict__ lo0,
                             bf16* __restrict__ hi1, bf16* __restrict__ lo1,
                             bf16* __restrict__ hi2, bf16* __restrict__ lo2) {
  const float* src; bf16* dh; bf16* dl;
  switch (blockIdx.z) {
    case 0: src = Wq; dh = hi0; dl = lo0; break;
    case 1: src = Wk; dh = hi1; dl = lo1; break;
    default: src = Wc; dh = hi2; dl = lo2; break;
  }
  __shared__ float s[32][33];
  int c = threadIdx.x & 31, r0 = threadIdx.x >> 5;
  int br = blockIdx.y * 32, bc = blockIdx.x * 32;
  for (int rr = r0; rr < 32; rr += 8) s[rr][c] = src[(br + rr) * 256 + bc + c];
  __syncthreads();
  for (int rr = r0; rr < 32; rr += 8) {
    float v = s[c][rr];
    bf16 h = (bf16)v;
    dh[(bc + rr) * 256 + br + c] = h;
    dl[(bc + rr) * 256 + br + c] = (bf16)(v - (float)h);
  }
}

// ---------------------------------------------------------------------------
// Split-precision GEMM: C[M,256] = A_f32[M,256] @ W + bias, W as split WT.
// acc = ahi*whi + ahi*wlo + alo*whi  (near-f32 exact).
// storeT==0: store split pair Chi/Clo row-major.  storeT==1: single bf16 in
// [b][n][L] (vT) layout. grid (M/128, 4), block 256.
// ---------------------------------------------------------------------------
__global__ __launch_bounds__(256) void gemm_split(const float* __restrict__ A,
                                                  const bf16* __restrict__ WThi,
                                                  const bf16* __restrict__ WTlo,
                                                  const float* __restrict__ bias,
                                                  bf16* __restrict__ Chi,
                                                  bf16* __restrict__ Clo, int storeT) {
  int tid = threadIdx.x;
  int wid = tid >> 6, lane = tid & 63, l15 = lane & 15, quad = lane >> 4;
  int mw = blockIdx.x * 128 + wid * 32;
  int nb = blockIdx.y * 64;

  f32x4 acc[2][4] = {};
  const float* a0p = A + (size_t)(mw + l15) * 256 + quad * 8;
  const float* a1p = a0p + 16 * 256;

#pragma unroll
  for (int ks = 0; ks < 8; ++ks) {
    int kb = ks * 32;
    bf16x8 a0h, a0l, a1h, a1l;
    split8(a0p + kb, a0h, a0l);
    split8(a1p + kb, a1h, a1l);
#pragma unroll
    for (int nt = 0; nt < 4; ++nt) {
      size_t woff = (size_t)(nb + nt * 16 + l15) * 256 + kb + quad * 8;
      bf16x8 wh = *(const bf16x8*)(WThi + woff);
      bf16x8 wl = *(const bf16x8*)(WTlo + woff);
      acc[0][nt] = MFMA16(a0l, wh, MFMA16(a0h, wl, MFMA16(a0h, wh, acc[0][nt])));
      acc[1][nt] = MFMA16(a1l, wh, MFMA16(a1h, wl, MFMA16(a1h, wh, acc[1][nt])));
    }
  }

#pragma unroll
  for (int nt = 0; nt < 4; ++nt) {
    int n = nb + nt * 16 + l15;
    float bv = bias[n];
#pragma unroll
    for (int mt = 0; mt < 2; ++mt) {
      int mbase = mw + mt * 16 + quad * 4;
      if (!storeT) {
#pragma unroll
        for (int r = 0; r < 4; ++r) {
          float v = acc[mt][nt][r] + bv;
          bf16 h = (bf16)v;
          Chi[(size_t)(mbase + r) * 256 + n] = h;
          Clo[(size_t)(mbase + r) * 256 + n] = (bf16)(v - (float)h);
        }
      } else {
        int b = mbase >> 12;
        int l = mbase & (L_ - 1);
        bf16x4 pv;
#pragma unroll
        for (int r = 0; r < 4; ++r) pv[r] = (bf16)(acc[mt][nt][r] + bv);
        *(bf16x4*)(Chi + ((size_t)b * 256 + n) * L_ + l) = pv;
      }
    }
  }
}

// ---------------------------------------------------------------------------
// Pass 1: banded scores (split-precision QK^T) + softmax; zero own 32 attn
// rows then write the f32 band. grid (L/32, B), block 256.
// ---------------------------------------------------------------------------
__global__ __launch_bounds__(256) void attn_pass1(const bf16* __restrict__ qhi,
                                                  const bf16* __restrict__ qlo,
                                                  const bf16* __restrict__ khi,
                                                  const bf16* __restrict__ klo,
                                                  float* __restrict__ attn) {
  int i0 = blockIdx.x * 32;
  int b = blockIdx.y;
  int tid = threadIdx.x;
  int wid = tid >> 6, lane = tid & 63, l15 = lane & 15, quad = lane >> 4;

  int jlo = imax(0, i0 - W_);
  int jhi = imin(L_, i0 + 32 + W_);
  int span = jhi - jlo;   // multiple of 32, <= 288
  int nch = span >> 5;

  __shared__ float sc[32][292];

  // zero own 32 full rows (f32)
  {
    uint4 z = {0u, 0u, 0u, 0u};
    uint4* dst = (uint4*)(attn + (size_t)(b * L_ + i0) * L_);
    for (int idx = tid; idx < 32 * L_ / 4; idx += 256) dst[idx] = z;
  }

  // band scores: 3-MFMA split product
  size_t q0 = (size_t)(b * L_ + i0 + l15) * 256 + quad * 8;
  size_t q1 = q0 + 16 * 256;
  for (int c = wid; c < nch; c += 4) {
    int jb = jlo + c * 32;
    size_t k0 = (size_t)(b * L_ + jb + l15) * 256 + quad * 8;
    size_t k1 = k0 + 16 * 256;
    f32x4 acc[2][2] = {};
#pragma unroll
    for (int ks = 0; ks < 8; ++ks) {
      int off = ks * 32;
      bf16x8 a0h = *(const bf16x8*)(qhi + q0 + off);
      bf16x8 a0l = *(const bf16x8*)(qlo + q0 + off);
      bf16x8 a1h = *(const bf16x8*)(qhi + q1 + off);
      bf16x8 a1l = *(const bf16x8*)(qlo + q1 + off);
      bf16x8 b0h = *(const bf16x8*)(khi + k0 + off);
      bf16x8 b0l = *(const bf16x8*)(klo + k0 + off);
      bf16x8 b1h = *(const bf16x8*)(khi + k1 + off);
      bf16x8 b1l = *(const bf16x8*)(klo + k1 + off);
      acc[0][0] = MFMA16(a0l, b0h, MFMA16(a0h, b0l, MFMA16(a0h, b0h, acc[0][0])));
      acc[0][1] = MFMA16(a0l, b1h, MFMA16(a0h, b1l, MFMA16(a0h, b1h, acc[0][1])));
      acc[1][0] = MFMA16(a1l, b0h, MFMA16(a1h, b0l, MFMA16(a1h, b0h, acc[1][0])));
      acc[1][1] = MFMA16(a1l, b1h, MFMA16(a1h, b1l, MFMA16(a1h, b1h, acc[1][1])));
    }
#pragma unroll
    for (int mt = 0; mt < 2; ++mt)
#pragma unroll
      for (int nt = 0; nt < 2; ++nt)
#pragma unroll
        for (int r = 0; r < 4; ++r)
          sc[mt * 16 + quad * 4 + r][c * 32 + nt * 16 + l15] = acc[mt][nt][r];
  }
  __syncthreads();

  // masked softmax, 8 threads per row
  {
    int r = tid >> 3, s = tid & 7;
    int ig = i0 + r;
    float m = -1e30f;
    for (int jj = s; jj < span; jj += 8) {
      int jg = jlo + jj;
      if (jg >= ig - W_ && jg <= ig + W_) m = fmaxf(m, sc[r][jj]);
    }
#pragma unroll
    for (int off = 1; off < 8; off <<= 1) m = fmaxf(m, __shfl_xor(m, off, 8));
    float sum = 0.f;
    for (int jj = s; jj < span; jj += 8) {
      int jg = jlo + jj;
      bool inb = (jg >= ig - W_ && jg <= ig + W_);
      float p = inb ? __expf(sc[r][jj] - m) : 0.f;
      sc[r][jj] = p;
      sum += p;
    }
#pragma unroll
    for (int off = 1; off < 8; off <<= 1) sum += __shfl_xor(sum, off, 8);
    float inv = 1.f / sum;
    for (int jj = s; jj < span; jj += 8) sc[r][jj] *= inv;
  }
  __syncthreads();

  // write band (f32)
  {
    float* arow = attn + (size_t)(b * L_ + i0) * L_ + jlo;
    for (int rr = 0; rr < 32; ++rr)
      for (int j = tid; j < span; j += 256) arow[(size_t)rr * L_ + j] = sc[rr][j];
  }
}

// ---------------------------------------------------------------------------
// Pass 2: out[i,:] = sum_j P[i,j] * u[j,:]  (P read f32 from attn region,
// u in [b][n][L] layout). grid (L/32, B), block 256 (wave = 64 out cols).
// ---------------------------------------------------------------------------
__global__ __launch_bounds__(256) void attn_pass2(const float* __restrict__ attn,
                                                  const bf16* __restrict__ uT,
                                                  float* __restrict__ out) {
  int i0 = blockIdx.x * 32;
  int b = blockIdx.y;
  int tid = threadIdx.x;
  int wid = tid >> 6, lane = tid & 63, l15 = lane & 15, quad = lane >> 4;

  int jlo = imax(0, i0 - W_);
  int jhi = imin(L_, i0 + 32 + W_);
  int nch = (jhi - jlo) >> 5;

  f32x4 acc[2][4] = {};
  const float* p0 = attn + (size_t)(b * L_ + i0 + l15) * L_ + jlo;
  const float* p1 = p0 + (size_t)16 * L_;

  for (int kc = 0; kc < nch; ++kc) {
    int kb = kc * 32 + quad * 8;
    bf16x8 a0 = cvt8(p0 + kb);
    bf16x8 a1 = cvt8(p1 + kb);
#pragma unroll
    for (int nt = 0; nt < 4; ++nt) {
      const bf16* up = uT + ((size_t)b * 256 + wid * 64 + nt * 16 + l15) * L_ + jlo + kb;
      bf16x8 uf = *(const bf16x8*)up;
      acc[0][nt] = MFMA16(a0, uf, acc[0][nt]);
      acc[1][nt] = MFMA16(a1, uf, acc[1][nt]);
    }
  }

#pragma unroll
  for (int nt = 0; nt < 4; ++nt) {
    int n = wid * 64 + nt * 16 + l15;
#pragma unroll
    for (int mt = 0; mt < 2; ++mt) {
      int row = i0 + mt * 16 + quad * 4;
#pragma unroll
      for (int r = 0; r < 4; ++r)
        out[(size_t)(b * L_ + row + r) * 256 + n] = acc[mt][nt][r];
    }
  }
}

// ---------------------------------------------------------------------------
extern "C" void kernel_launch(void* const* d_in, const int* in_sizes, int n_in,
                              void* d_out, int out_size, void* d_ws, size_t ws_size,
                              hipStream_t stream) {
  (void)in_sizes; (void)n_in; (void)out_size; (void)ws_size;

  const float* query = (const float*)d_in[0];
  const float* key   = (const float*)d_in[1];
  const float* value = (const float*)d_in[2];
  const float* Wq = (const float*)d_in[3];
  const float* bq = (const float*)d_in[4];
  const float* Wk = (const float*)d_in[5];
  const float* bk = (const float*)d_in[6];
  const float* Wv = (const float*)d_in[7];
  const float* bv = (const float*)d_in[8];
  const float* Wo = (const float*)d_in[9];
  const float* bo = (const float*)d_in[10];

  float* out    = (float*)d_out;                 // [B, L, 256] f32
  float* attn_f = out + (size_t)B_ * L_ * D_;    // [B, L, L]   f32

  // ws (~13.3 MB): Wc f32 + bc f32 + 6 split weight mats + khi + klo + uT
  char* ws = (char*)d_ws;
  const size_t WSZ = 256 * 256;             // elems per weight matrix
  const size_t MSZ = (size_t)B_ * L_ * D_;  // elems per activation matrix
  float* Wc = (float*)ws;                          // 256 KB
  float* bc = (float*)(ws + WSZ * 4);              // 1 KB
  bf16* wqThi = (bf16*)(ws + WSZ * 4 + 4096);
  bf16* wqTlo = wqThi + WSZ;
  bf16* wkThi = wqTlo + WSZ;
  bf16* wkTlo = wkThi + WSZ;
  bf16* wcThi = wkTlo + WSZ;
  bf16* wcTlo = wcThi + WSZ;
  bf16* khi = wcTlo + WSZ;    // 4 MB
  bf16* klo = khi + MSZ;      // 4 MB
  bf16* uT  = klo + MSZ;      // 4 MB, [b][n][L]
  // q hi/lo park in the out[B,L,256] f32 region (8 MB = exactly 2 bf16 mats);
  // dead after pass1; out region written only by pass2 (separate launch).
  bf16* qhi = (bf16*)out;
  bf16* qlo = qhi + MSZ;

  make_wc<<<256, 256, 0, stream>>>(Wv, Wo, bv, bo, Wc, bc);
  prep_weights<<<dim3(8, 8, 3), 256, 0, stream>>>(Wq, Wk, Wc, wqThi, wqTlo,
                                                  wkThi, wkTlo, wcThi, wcTlo);
  gemm_split<<<dim3(64, 4), 256, 0, stream>>>(query, wqThi, wqTlo, bq, qhi, qlo, 0);
  gemm_split<<<dim3(64, 4), 256, 0, stream>>>(key,   wkThi, wkTlo, bk, khi, klo, 0);
  gemm_split<<<dim3(64, 4), 256, 0, stream>>>(value, wcThi, wcTlo, bc, uT,  uT,  1);
  attn_pass1<<<dim3(L_ / 32, B_), 256, 0, stream>>>(qhi, qlo, khi, klo, attn_f);
  attn_pass2<<<dim3(L_ / 32, B_), 256, 0, stream>>>(attn_f, uT, out);
}

// Round 6
// 273.260 us; speedup vs baseline: 1.1133x; 1.1133x over previous
//
#include <hip/hip_runtime.h>

#define B_ 2
#define L_ 4096
#define D_ 256
#define W_ 128

typedef __bf16 bf16;
typedef __bf16 bf16x8 __attribute__((ext_vector_type(8)));
typedef __bf16 bf16x4 __attribute__((ext_vector_type(4)));
typedef float f32x4 __attribute__((ext_vector_type(4)));

#define MFMA16(a, b, c) __builtin_amdgcn_mfma_f32_16x16x32_bf16((a), (b), (c), 0, 0, 0)

__device__ __forceinline__ int imin(int a, int b) { return a < b ? a : b; }
__device__ __forceinline__ int imax(int a, int b) { return a > b ? a : b; }

// Split 8 consecutive f32 into hi/lo bf16 fragments (hi = rn(x), lo = rn(x-hi)).
__device__ __forceinline__ void split8(const float* p, bf16x8& hi, bf16x8& lo) {
  f32x4 v0 = ((const f32x4*)p)[0], v1 = ((const f32x4*)p)[1];
#pragma unroll
  for (int j = 0; j < 4; ++j) {
    bf16 h0 = (bf16)v0[j]; hi[j] = h0; lo[j] = (bf16)(v0[j] - (float)h0);
    bf16 h1 = (bf16)v1[j]; hi[j + 4] = h1; lo[j + 4] = (bf16)(v1[j] - (float)h1);
  }
}

// Convert 8 consecutive f32 to bf16x8 (single rounding).
__device__ __forceinline__ bf16x8 cvt8(const float* p) {
  f32x4 v0 = ((const f32x4*)p)[0], v1 = ((const f32x4*)p)[1];
  bf16x8 r;
#pragma unroll
  for (int j = 0; j < 4; ++j) { r[j] = (bf16)v0[j]; r[j + 4] = (bf16)v1[j]; }
  return r;
}

// ---------------------------------------------------------------------------
// Kernel A: fused prep. 1-D grid of 2432 blocks x 256 threads:
//   [0,2048)      zero the 128 MB f32 attn region (64 KB per block)
//   [2048,2176)   transpose-split Wq (first 64) / Wk (next 64) into bf16 hi/lo
//   [2176,2432)   row i of Wc = Wv@Wo (f32, 8-way ILP), written transposed
//                 split; block i==0 also computes bc = bv@Wo + bo.
// All parts independent; zero-fill store BW hides weight-prep latency.
// ---------------------------------------------------------------------------
__global__ __launch_bounds__(256) void prep_zero(
    const float* __restrict__ Wq, const float* __restrict__ Wk,
    const float* __restrict__ Wv, const float* __restrict__ Wo,
    const float* __restrict__ bv, const float* __restrict__ bo,
    bf16* __restrict__ wqThi, bf16* __restrict__ wqTlo,
    bf16* __restrict__ wkThi, bf16* __restrict__ wkTlo,
    bf16* __restrict__ wcThi, bf16* __restrict__ wcTlo,
    float* __restrict__ bc, float* __restrict__ attn) {
  int blk = blockIdx.x;
  if (blk < 2048) {
    uint4 z = {0u, 0u, 0u, 0u};
    uint4* dst = (uint4*)attn + (size_t)blk * 4096;
    for (int i = threadIdx.x; i < 4096; i += 256) dst[i] = z;
    return;
  }
  blk -= 2048;
  if (blk < 128) {
    int m = blk >> 6;  // 0: Wq, 1: Wk
    int t = blk & 63;
    int bx = t & 7, by = t >> 3;
    const float* src = m ? Wk : Wq;
    bf16* dh = m ? wkThi : wqThi;
    bf16* dl = m ? wkTlo : wqTlo;
    __shared__ float s[32][33];
    int c = threadIdx.x & 31, r0 = threadIdx.x >> 5;
    int br = by * 32, bcc = bx * 32;
    for (int rr = r0; rr < 32; rr += 8) s[rr][c] = src[(br + rr) * 256 + bcc + c];
    __syncthreads();
    for (int rr = r0; rr < 32; rr += 8) {
      float v = s[c][rr];
      bf16 h = (bf16)v;
      dh[(bcc + rr) * 256 + br + c] = h;
      dl[(bcc + rr) * 256 + br + c] = (bf16)(v - (float)h);
    }
    return;
  }
  blk -= 128;  // blk = row i of Wc
  int i = blk, j = threadIdx.x;
  float acc[8] = {};
  for (int k0 = 0; k0 < 256; k0 += 8) {
#pragma unroll
    for (int t = 0; t < 8; ++t)
      acc[t] = fmaf(Wv[i * 256 + k0 + t], Wo[(k0 + t) * 256 + j], acc[t]);
  }
  float s = ((acc[0] + acc[1]) + (acc[2] + acc[3])) + ((acc[4] + acc[5]) + (acc[6] + acc[7]));
  bf16 h = (bf16)s;
  wcThi[j * 256 + i] = h;                 // wcT[n=j][k=i]
  wcTlo[j * 256 + i] = (bf16)(s - (float)h);
  if (i == 0) {
    float bacc[8] = {};
    for (int k0 = 0; k0 < 256; k0 += 8) {
#pragma unroll
      for (int t = 0; t < 8; ++t)
        bacc[t] = fmaf(bv[k0 + t], Wo[(k0 + t) * 256 + j], bacc[t]);
    }
    bc[j] = ((bacc[0] + bacc[1]) + (bacc[2] + bacc[3])) +
            ((bacc[4] + bacc[5]) + (bacc[6] + bacc[7])) + bo[j];
  }
}

// ---------------------------------------------------------------------------
// Kernel B: the three independent projections in one launch.
// z=0: q = query@Wq+bq (split store)  z=1: k = key@Wk+bk (split store)
// z=2: u = value@Wc+bc (bf16, [b][n][L] layout)
// grid (64,4,3), block 256 (4 waves; wave = 32 rows x 64 cols)
// ---------------------------------------------------------------------------
__global__ __launch_bounds__(256) void gemm3(
    const float* __restrict__ query, const float* __restrict__ key,
    const float* __restrict__ value,
    const bf16* __restrict__ wqThi, const bf16* __restrict__ wqTlo,
    const bf16* __restrict__ wkThi, const bf16* __restrict__ wkTlo,
    const bf16* __restrict__ wcThi, const bf16* __restrict__ wcTlo,
    const float* __restrict__ bq, const float* __restrict__ bk,
    const float* __restrict__ bc,
    bf16* __restrict__ qhi, bf16* __restrict__ qlo,
    bf16* __restrict__ khi, bf16* __restrict__ klo, bf16* __restrict__ uT) {
  const float* A; const bf16 *WThi, *WTlo; const float* bias;
  bf16 *Chi, *Clo; int storeT;
  switch (blockIdx.z) {
    case 0: A = query; WThi = wqThi; WTlo = wqTlo; bias = bq; Chi = qhi; Clo = qlo; storeT = 0; break;
    case 1: A = key;   WThi = wkThi; WTlo = wkTlo; bias = bk; Chi = khi; Clo = klo; storeT = 0; break;
    default: A = value; WThi = wcThi; WTlo = wcTlo; bias = bc; Chi = uT; Clo = uT; storeT = 1; break;
  }
  int tid = threadIdx.x;
  int wid = tid >> 6, lane = tid & 63, l15 = lane & 15, quad = lane >> 4;
  int mw = blockIdx.x * 128 + wid * 32;
  int nb = blockIdx.y * 64;

  f32x4 acc[2][4] = {};
  const float* a0p = A + (size_t)(mw + l15) * 256 + quad * 8;
  const float* a1p = a0p + 16 * 256;

#pragma unroll
  for (int ks = 0; ks < 8; ++ks) {
    int kb = ks * 32;
    bf16x8 a0h, a0l, a1h, a1l;
    split8(a0p + kb, a0h, a0l);
    split8(a1p + kb, a1h, a1l);
#pragma unroll
    for (int nt = 0; nt < 4; ++nt) {
      size_t woff = (size_t)(nb + nt * 16 + l15) * 256 + kb + quad * 8;
      bf16x8 wh = *(const bf16x8*)(WThi + woff);
      bf16x8 wl = *(const bf16x8*)(WTlo + woff);
      acc[0][nt] = MFMA16(a0l, wh, MFMA16(a0h, wl, MFMA16(a0h, wh, acc[0][nt])));
      acc[1][nt] = MFMA16(a1l, wh, MFMA16(a1h, wl, MFMA16(a1h, wh, acc[1][nt])));
    }
  }

#pragma unroll
  for (int nt = 0; nt < 4; ++nt) {
    int n = nb + nt * 16 + l15;
    float bvv = bias[n];
#pragma unroll
    for (int mt = 0; mt < 2; ++mt) {
      int mbase = mw + mt * 16 + quad * 4;
      if (!storeT) {
#pragma unroll
        for (int r = 0; r < 4; ++r) {
          float v = acc[mt][nt][r] + bvv;
          bf16 h = (bf16)v;
          Chi[(size_t)(mbase + r) * 256 + n] = h;
          Clo[(size_t)(mbase + r) * 256 + n] = (bf16)(v - (float)h);
        }
      } else {
        int b = mbase >> 12;
        int l = mbase & (L_ - 1);
        bf16x4 pv;
#pragma unroll
        for (int r = 0; r < 4; ++r) pv[r] = (bf16)(acc[mt][nt][r] + bvv);
        *(bf16x4*)(Chi + ((size_t)b * 256 + n) * L_ + l) = pv;
      }
    }
  }
}

// ---------------------------------------------------------------------------
// Pass 1: banded scores (split-precision QK^T) + softmax; write f32 band only
// (out-of-band zeros already written by prep_zero). grid (L/32, B), block 256.
// ---------------------------------------------------------------------------
__global__ __launch_bounds__(256) void attn_pass1(const bf16* __restrict__ qhi,
                                                  const bf16* __restrict__ qlo,
                                                  const bf16* __restrict__ khi,
                                                  const bf16* __restrict__ klo,
                                                  float* __restrict__ attn) {
  int i0 = blockIdx.x * 32;
  int b = blockIdx.y;
  int tid = threadIdx.x;
  int wid = tid >> 6, lane = tid & 63, l15 = lane & 15, quad = lane >> 4;

  int jlo = imax(0, i0 - W_);
  int jhi = imin(L_, i0 + 32 + W_);
  int span = jhi - jlo;   // multiple of 32, <= 288
  int nch = span >> 5;

  __shared__ float sc[32][292];

  size_t q0 = (size_t)(b * L_ + i0 + l15) * 256 + quad * 8;
  size_t q1 = q0 + 16 * 256;
  for (int c = wid; c < nch; c += 4) {
    int jb = jlo + c * 32;
    size_t k0 = (size_t)(b * L_ + jb + l15) * 256 + quad * 8;
    size_t k1 = k0 + 16 * 256;
    f32x4 acc[2][2] = {};
#pragma unroll
    for (int ks = 0; ks < 8; ++ks) {
      int off = ks * 32;
      bf16x8 a0h = *(const bf16x8*)(qhi + q0 + off);
      bf16x8 a0l = *(const bf16x8*)(qlo + q0 + off);
      bf16x8 a1h = *(const bf16x8*)(qhi + q1 + off);
      bf16x8 a1l = *(const bf16x8*)(qlo + q1 + off);
      bf16x8 b0h = *(const bf16x8*)(khi + k0 + off);
      bf16x8 b0l = *(const bf16x8*)(klo + k0 + off);
      bf16x8 b1h = *(const bf16x8*)(khi + k1 + off);
      bf16x8 b1l = *(const bf16x8*)(klo + k1 + off);
      acc[0][0] = MFMA16(a0l, b0h, MFMA16(a0h, b0l, MFMA16(a0h, b0h, acc[0][0])));
      acc[0][1] = MFMA16(a0l, b1h, MFMA16(a0h, b1l, MFMA16(a0h, b1h, acc[0][1])));
      acc[1][0] = MFMA16(a1l, b0h, MFMA16(a1h, b0l, MFMA16(a1h, b0h, acc[1][0])));
      acc[1][1] = MFMA16(a1l, b1h, MFMA16(a1h, b1l, MFMA16(a1h, b1h, acc[1][1])));
    }
#pragma unroll
    for (int mt = 0; mt < 2; ++mt)
#pragma unroll
      for (int nt = 0; nt < 2; ++nt)
#pragma unroll
        for (int r = 0; r < 4; ++r)
          sc[mt * 16 + quad * 4 + r][c * 32 + nt * 16 + l15] = acc[mt][nt][r];
  }
  __syncthreads();

  // masked softmax, 8 threads per row
  {
    int r = tid >> 3, s = tid & 7;
    int ig = i0 + r;
    float m = -1e30f;
    for (int jj = s; jj < span; jj += 8) {
      int jg = jlo + jj;
      if (jg >= ig - W_ && jg <= ig + W_) m = fmaxf(m, sc[r][jj]);
    }
#pragma unroll
    for (int off = 1; off < 8; off <<= 1) m = fmaxf(m, __shfl_xor(m, off, 8));
    float sum = 0.f;
    for (int jj = s; jj < span; jj += 8) {
      int jg = jlo + jj;
      bool inb = (jg >= ig - W_ && jg <= ig + W_);
      float p = inb ? __expf(sc[r][jj] - m) : 0.f;
      sc[r][jj] = p;
      sum += p;
    }
#pragma unroll
    for (int off = 1; off < 8; off <<= 1) sum += __shfl_xor(sum, off, 8);
    float inv = 1.f / sum;
    for (int jj = s; jj < span; jj += 8) sc[r][jj] *= inv;
  }
  __syncthreads();

  // write band (f32)
  {
    float* arow = attn + (size_t)(b * L_ + i0) * L_ + jlo;
    for (int rr = 0; rr < 32; ++rr)
      for (int j = tid; j < span; j += 256) arow[(size_t)rr * L_ + j] = sc[rr][j];
  }
}

// ---------------------------------------------------------------------------
// Pass 2: out[i,:] = sum_j P[i,j] * u[j,:]  (P read f32 from attn region,
// u in [b][n][L] layout). grid (L/32, B), block 256 (wave = 64 out cols).
// ---------------------------------------------------------------------------
__global__ __launch_bounds__(256) void attn_pass2(const float* __restrict__ attn,
                                                  const bf16* __restrict__ uT,
                                                  float* __restrict__ out) {
  int i0 = blockIdx.x * 32;
  int b = blockIdx.y;
  int tid = threadIdx.x;
  int wid = tid >> 6, lane = tid & 63, l15 = lane & 15, quad = lane >> 4;

  int jlo = imax(0, i0 - W_);
  int jhi = imin(L_, i0 + 32 + W_);
  int nch = (jhi - jlo) >> 5;

  f32x4 acc[2][4] = {};
  const float* p0 = attn + (size_t)(b * L_ + i0 + l15) * L_ + jlo;
  const float* p1 = p0 + (size_t)16 * L_;

  for (int kc = 0; kc < nch; ++kc) {
    int kb = kc * 32 + quad * 8;
    bf16x8 a0 = cvt8(p0 + kb);
    bf16x8 a1 = cvt8(p1 + kb);
#pragma unroll
    for (int nt = 0; nt < 4; ++nt) {
      const bf16* up = uT + ((size_t)b * 256 + wid * 64 + nt * 16 + l15) * L_ + jlo + kb;
      bf16x8 uf = *(const bf16x8*)up;
      acc[0][nt] = MFMA16(a0, uf, acc[0][nt]);
      acc[1][nt] = MFMA16(a1, uf, acc[1][nt]);
    }
  }

#pragma unroll
  for (int nt = 0; nt < 4; ++nt) {
    int n = wid * 64 + nt * 16 + l15;
#pragma unroll
    for (int mt = 0; mt < 2; ++mt) {
      int row = i0 + mt * 16 + quad * 4;
#pragma unroll
      for (int r = 0; r < 4; ++r)
        out[(size_t)(b * L_ + row + r) * 256 + n] = acc[mt][nt][r];
    }
  }
}

// ---------------------------------------------------------------------------
extern "C" void kernel_launch(void* const* d_in, const int* in_sizes, int n_in,
                              void* d_out, int out_size, void* d_ws, size_t ws_size,
                              hipStream_t stream) {
  (void)in_sizes; (void)n_in; (void)out_size; (void)ws_size;

  const float* query = (const float*)d_in[0];
  const float* key   = (const float*)d_in[1];
  const float* value = (const float*)d_in[2];
  const float* Wq = (const float*)d_in[3];
  const float* bq = (const float*)d_in[4];
  const float* Wk = (const float*)d_in[5];
  const float* bk = (const float*)d_in[6];
  const float* Wv = (const float*)d_in[7];
  const float* bv = (const float*)d_in[8];
  const float* Wo = (const float*)d_in[9];
  const float* bo = (const float*)d_in[10];

  float* out    = (float*)d_out;                 // [B, L, 256] f32
  float* attn_f = out + (size_t)B_ * L_ * D_;    // [B, L, L]   f32

  // ws (~12.8 MB): bc + 6 split weight mats + khi + klo + uT
  char* ws = (char*)d_ws;
  const size_t WSZ = 256 * 256;
  const size_t MSZ = (size_t)B_ * L_ * D_;
  float* bc = (float*)ws;                    // 1 KB (pad to 4 KB)
  bf16* wqThi = (bf16*)(ws + 4096);
  bf16* wqTlo = wqThi + WSZ;
  bf16* wkThi = wqTlo + WSZ;
  bf16* wkTlo = wkThi + WSZ;
  bf16* wcThi = wkTlo + WSZ;
  bf16* wcTlo = wcThi + WSZ;
  bf16* khi = wcTlo + WSZ;    // 4 MB
  bf16* klo = khi + MSZ;      // 4 MB
  bf16* uT  = klo + MSZ;      // 4 MB, [b][n][L]
  // q hi/lo park in the out[B,L,256] f32 region (8 MB = exactly 2 bf16 mats);
  // dead after pass1; out region written only by pass2 (separate launch).
  bf16* qhi = (bf16*)out;
  bf16* qlo = qhi + MSZ;

  prep_zero<<<2432, 256, 0, stream>>>(Wq, Wk, Wv, Wo, bv, bo,
                                      wqThi, wqTlo, wkThi, wkTlo, wcThi, wcTlo,
                                      bc, attn_f);
  gemm3<<<dim3(64, 4, 3), 256, 0, stream>>>(query, key, value,
                                            wqThi, wqTlo, wkThi, wkTlo, wcThi, wcTlo,
                                            bq, bk, bc, qhi, qlo, khi, klo, uT);
  attn_pass1<<<dim3(L_ / 32, B_), 256, 0, stream>>>(qhi, qlo, khi, klo, attn_f);
  attn_pass2<<<dim3(L_ / 32, B_), 256, 0, stream>>>(attn_f, uT, out);
}

// Round 7
// 267.246 us; speedup vs baseline: 1.1384x; 1.0225x over previous
//
#include <hip/hip_runtime.h>

#define B_ 2
#define L_ 4096
#define D_ 256
#define W_ 128

typedef __bf16 bf16;
typedef __bf16 bf16x8 __attribute__((ext_vector_type(8)));
typedef __bf16 bf16x4 __attribute__((ext_vector_type(4)));
typedef float f32x4 __attribute__((ext_vector_type(4)));

#define MFMA16(a, b, c) __builtin_amdgcn_mfma_f32_16x16x32_bf16((a), (b), (c), 0, 0, 0)

__device__ __forceinline__ int imin(int a, int b) { return a < b ? a : b; }
__device__ __forceinline__ int imax(int a, int b) { return a > b ? a : b; }

// Split 8 consecutive f32 into hi/lo bf16 fragments (hi = rn(x), lo = rn(x-hi)).
__device__ __forceinline__ void split8(const float* p, bf16x8& hi, bf16x8& lo) {
  f32x4 v0 = ((const f32x4*)p)[0], v1 = ((const f32x4*)p)[1];
#pragma unroll
  for (int j = 0; j < 4; ++j) {
    bf16 h0 = (bf16)v0[j]; hi[j] = h0; lo[j] = (bf16)(v0[j] - (float)h0);
    bf16 h1 = (bf16)v1[j]; hi[j + 4] = h1; lo[j + 4] = (bf16)(v1[j] - (float)h1);
  }
}

// ---------------------------------------------------------------------------
// prep_w: 384 blocks x 256 threads.
//   [0,64)    transpose-split Wq -> wqThi/lo     [64,128) same for Wk
//   [128,384) row i=blk-128 of Wc = Wv@Wo (f32, 8-way ILP), stored
//             transposed-split; block i==0 also computes bc = bv@Wo + bo.
// ---------------------------------------------------------------------------
__global__ __launch_bounds__(256) void prep_w(
    const float* __restrict__ Wq, const float* __restrict__ Wk,
    const float* __restrict__ Wv, const float* __restrict__ Wo,
    const float* __restrict__ bv, const float* __restrict__ bo,
    bf16* __restrict__ wqThi, bf16* __restrict__ wqTlo,
    bf16* __restrict__ wkThi, bf16* __restrict__ wkTlo,
    bf16* __restrict__ wcThi, bf16* __restrict__ wcTlo,
    float* __restrict__ bc) {
  int blk = blockIdx.x;
  if (blk < 128) {
    int m = blk >> 6;  // 0: Wq, 1: Wk
    int t = blk & 63;
    int bx = t & 7, by = t >> 3;
    const float* src = m ? Wk : Wq;
    bf16* dh = m ? wkThi : wqThi;
    bf16* dl = m ? wkTlo : wqTlo;
    __shared__ float s[32][33];
    int c = threadIdx.x & 31, r0 = threadIdx.x >> 5;
    int br = by * 32, bcc = bx * 32;
    for (int rr = r0; rr < 32; rr += 8) s[rr][c] = src[(br + rr) * 256 + bcc + c];
    __syncthreads();
    for (int rr = r0; rr < 32; rr += 8) {
      float v = s[c][rr];
      bf16 h = (bf16)v;
      dh[(bcc + rr) * 256 + br + c] = h;
      dl[(bcc + rr) * 256 + br + c] = (bf16)(v - (float)h);
    }
    return;
  }
  int i = blk - 128, j = threadIdx.x;
  float acc[8] = {};
  for (int k0 = 0; k0 < 256; k0 += 8) {
#pragma unroll
    for (int t = 0; t < 8; ++t)
      acc[t] = fmaf(Wv[i * 256 + k0 + t], Wo[(k0 + t) * 256 + j], acc[t]);
  }
  float s = ((acc[0] + acc[1]) + (acc[2] + acc[3])) + ((acc[4] + acc[5]) + (acc[6] + acc[7]));
  bf16 h = (bf16)s;
  wcThi[j * 256 + i] = h;  // wcT[n=j][k=i]
  wcTlo[j * 256 + i] = (bf16)(s - (float)h);
  if (i == 0) {
    float bacc[8] = {};
    for (int k0 = 0; k0 < 256; k0 += 8) {
#pragma unroll
      for (int t = 0; t < 8; ++t)
        bacc[t] = fmaf(bv[k0 + t], Wo[(k0 + t) * 256 + j], bacc[t]);
    }
    bc[j] = ((bacc[0] + bacc[1]) + (bacc[2] + bacc[3])) +
            ((bacc[4] + bacc[5]) + (bacc[6] + bacc[7])) + bo[j];
  }
}

// ---------------------------------------------------------------------------
// gemm3: three independent projections in one launch.
// z=0: q = query@Wq+bq (split store)  z=1: k = key@Wk+bk (split store)
// z=2: u = value@Wc+bc (bf16, [b][n][L] layout)
// grid (64,4,3), block 256 (4 waves; wave = 32 rows x 64 cols)
// ---------------------------------------------------------------------------
__global__ __launch_bounds__(256) void gemm3(
    const float* __restrict__ query, const float* __restrict__ key,
    const float* __restrict__ value,
    const bf16* __restrict__ wqThi, const bf16* __restrict__ wqTlo,
    const bf16* __restrict__ wkThi, const bf16* __restrict__ wkTlo,
    const bf16* __restrict__ wcThi, const bf16* __restrict__ wcTlo,
    const float* __restrict__ bq, const float* __restrict__ bk,
    const float* __restrict__ bc,
    bf16* __restrict__ qhi, bf16* __restrict__ qlo,
    bf16* __restrict__ khi, bf16* __restrict__ klo, bf16* __restrict__ uT) {
  const float* A; const bf16 *WThi, *WTlo; const float* bias;
  bf16 *Chi, *Clo; int storeT;
  switch (blockIdx.z) {
    case 0: A = query; WThi = wqThi; WTlo = wqTlo; bias = bq; Chi = qhi; Clo = qlo; storeT = 0; break;
    case 1: A = key;   WThi = wkThi; WTlo = wkTlo; bias = bk; Chi = khi; Clo = klo; storeT = 0; break;
    default: A = value; WThi = wcThi; WTlo = wcTlo; bias = bc; Chi = uT; Clo = uT; storeT = 1; break;
  }
  int tid = threadIdx.x;
  int wid = tid >> 6, lane = tid & 63, l15 = lane & 15, quad = lane >> 4;
  int mw = blockIdx.x * 128 + wid * 32;
  int nb = blockIdx.y * 64;

  f32x4 acc[2][4] = {};
  const float* a0p = A + (size_t)(mw + l15) * 256 + quad * 8;
  const float* a1p = a0p + 16 * 256;

#pragma unroll
  for (int ks = 0; ks < 8; ++ks) {
    int kb = ks * 32;
    bf16x8 a0h, a0l, a1h, a1l;
    split8(a0p + kb, a0h, a0l);
    split8(a1p + kb, a1h, a1l);
#pragma unroll
    for (int nt = 0; nt < 4; ++nt) {
      size_t woff = (size_t)(nb + nt * 16 + l15) * 256 + kb + quad * 8;
      bf16x8 wh = *(const bf16x8*)(WThi + woff);
      bf16x8 wl = *(const bf16x8*)(WTlo + woff);
      acc[0][nt] = MFMA16(a0l, wh, MFMA16(a0h, wl, MFMA16(a0h, wh, acc[0][nt])));
      acc[1][nt] = MFMA16(a1l, wh, MFMA16(a1h, wl, MFMA16(a1h, wh, acc[1][nt])));
    }
  }

#pragma unroll
  for (int nt = 0; nt < 4; ++nt) {
    int n = nb + nt * 16 + l15;
    float bvv = bias[n];
#pragma unroll
    for (int mt = 0; mt < 2; ++mt) {
      int mbase = mw + mt * 16 + quad * 4;
      if (!storeT) {
#pragma unroll
        for (int r = 0; r < 4; ++r) {
          float v = acc[mt][nt][r] + bvv;
          bf16 h = (bf16)v;
          Chi[(size_t)(mbase + r) * 256 + n] = h;
          Clo[(size_t)(mbase + r) * 256 + n] = (bf16)(v - (float)h);
        }
      } else {
        int b = mbase >> 12;
        int l = mbase & (L_ - 1);
        bf16x4 pv;
#pragma unroll
        for (int r = 0; r < 4; ++r) pv[r] = (bf16)(acc[mt][nt][r] + bvv);
        *(bf16x4*)(Chi + ((size_t)b * 256 + n) * L_ + l) = pv;
      }
    }
  }
}

// ---------------------------------------------------------------------------
// attn_fused: one block = 32 query rows of one batch.
//   1) split-precision QK^T band scores -> LDS
//   2) masked softmax in LDS
//   3) write full 32 attn rows (zeros + band), nontemporal f32
//   4) PV from LDS x uT -> out rows (f32)
// grid (L/32, B), block 256 (4 waves)
// ---------------------------------------------------------------------------
__global__ __launch_bounds__(256) void attn_fused(
    const bf16* __restrict__ qhi, const bf16* __restrict__ qlo,
    const bf16* __restrict__ khi, const bf16* __restrict__ klo,
    const bf16* __restrict__ uT, float* __restrict__ attn,
    float* __restrict__ out) {
  int i0 = blockIdx.x * 32;
  int b = blockIdx.y;
  int tid = threadIdx.x;
  int wid = tid >> 6, lane = tid & 63, l15 = lane & 15, quad = lane >> 4;

  int jlo = imax(0, i0 - W_);
  int jhi = imin(L_, i0 + 32 + W_);
  int span = jhi - jlo;   // multiple of 32, <= 288
  int nch = span >> 5;

  __shared__ float sc[32][292];

  // ---- 1) band scores: 3-MFMA split product
  size_t q0 = (size_t)(b * L_ + i0 + l15) * 256 + quad * 8;
  size_t q1 = q0 + 16 * 256;
  for (int c = wid; c < nch; c += 4) {
    int jb = jlo + c * 32;
    size_t k0 = (size_t)(b * L_ + jb + l15) * 256 + quad * 8;
    size_t k1 = k0 + 16 * 256;
    f32x4 acc[2][2] = {};
#pragma unroll
    for (int ks = 0; ks < 8; ++ks) {
      int off = ks * 32;
      bf16x8 a0h = *(const bf16x8*)(qhi + q0 + off);
      bf16x8 a0l = *(const bf16x8*)(qlo + q0 + off);
      bf16x8 a1h = *(const bf16x8*)(qhi + q1 + off);
      bf16x8 a1l = *(const bf16x8*)(qlo + q1 + off);
      bf16x8 b0h = *(const bf16x8*)(khi + k0 + off);
      bf16x8 b0l = *(const bf16x8*)(klo + k0 + off);
      bf16x8 b1h = *(const bf16x8*)(khi + k1 + off);
      bf16x8 b1l = *(const bf16x8*)(klo + k1 + off);
      acc[0][0] = MFMA16(a0l, b0h, MFMA16(a0h, b0l, MFMA16(a0h, b0h, acc[0][0])));
      acc[0][1] = MFMA16(a0l, b1h, MFMA16(a0h, b1l, MFMA16(a0h, b1h, acc[0][1])));
      acc[1][0] = MFMA16(a1l, b0h, MFMA16(a1h, b0l, MFMA16(a1h, b0h, acc[1][0])));
      acc[1][1] = MFMA16(a1l, b1h, MFMA16(a1h, b1l, MFMA16(a1h, b1h, acc[1][1])));
    }
#pragma unroll
    for (int mt = 0; mt < 2; ++mt)
#pragma unroll
      for (int nt = 0; nt < 2; ++nt)
#pragma unroll
        for (int r = 0; r < 4; ++r)
          sc[mt * 16 + quad * 4 + r][c * 32 + nt * 16 + l15] = acc[mt][nt][r];
  }
  __syncthreads();

  // ---- 2) masked softmax, 8 threads per row
  {
    int r = tid >> 3, s = tid & 7;
    int ig = i0 + r;
    float m = -1e30f;
    for (int jj = s; jj < span; jj += 8) {
      int jg = jlo + jj;
      if (jg >= ig - W_ && jg <= ig + W_) m = fmaxf(m, sc[r][jj]);
    }
#pragma unroll
    for (int off = 1; off < 8; off <<= 1) m = fmaxf(m, __shfl_xor(m, off, 8));
    float sum = 0.f;
    for (int jj = s; jj < span; jj += 8) {
      int jg = jlo + jj;
      bool inb = (jg >= ig - W_ && jg <= ig + W_);
      float p = inb ? __expf(sc[r][jj] - m) : 0.f;
      sc[r][jj] = p;
      sum += p;
    }
#pragma unroll
    for (int off = 1; off < 8; off <<= 1) sum += __shfl_xor(sum, off, 8);
    float inv = 1.f / sum;
    for (int jj = s; jj < span; jj += 8) sc[r][jj] *= inv;
  }
  __syncthreads();

  // ---- 3) write full 32 attn rows: zeros outside band, probs inside.
  for (int rr = 0; rr < 32; ++rr) {
    int ig = i0 + rr;
    float* arow = attn + (size_t)(b * L_ + ig) * L_;
    int slo = imax(0, ig - W_) >> 2;        // first uint4 slot touching band
    int shi = imin(L_ - 1, ig + W_) >> 2;   // last
    for (int s = tid; s < L_ / 4; s += 256) {
      f32x4 v = {0.f, 0.f, 0.f, 0.f};
      if (s >= slo && s <= shi) {
        int j0 = s * 4;
#pragma unroll
        for (int e = 0; e < 4; ++e) {
          int jg = j0 + e;
          bool inb = (jg >= ig - W_) && (jg <= ig + W_);
          int idx = imin(imax(jg - jlo, 0), 291);
          v[e] = inb ? sc[rr][idx] : 0.f;
        }
      }
      __builtin_nontemporal_store(v, (f32x4*)(arow + s * 4));
    }
  }

  // ---- 4) PV from LDS: out = P @ u  (wave w handles cols [w*64, w*64+64))
  {
    f32x4 acc[2][4] = {};
    for (int kc = 0; kc < nch; ++kc) {
      int kb = kc * 32 + quad * 8;
      bf16x8 a0, a1;
      {
        const f32x4* p0 = (const f32x4*)&sc[l15][kb];
        const f32x4* p1 = (const f32x4*)&sc[16 + l15][kb];
        f32x4 lo0 = p0[0], hi0 = p0[1], lo1 = p1[0], hi1 = p1[1];
#pragma unroll
        for (int j = 0; j < 4; ++j) {
          a0[j] = (bf16)lo0[j]; a0[j + 4] = (bf16)hi0[j];
          a1[j] = (bf16)lo1[j]; a1[j + 4] = (bf16)hi1[j];
        }
      }
#pragma unroll
      for (int nt = 0; nt < 4; ++nt) {
        const bf16* up = uT + ((size_t)b * 256 + wid * 64 + nt * 16 + l15) * L_ + jlo + kb;
        bf16x8 uf = *(const bf16x8*)up;
        acc[0][nt] = MFMA16(a0, uf, acc[0][nt]);
        acc[1][nt] = MFMA16(a1, uf, acc[1][nt]);
      }
    }
#pragma unroll
    for (int nt = 0; nt < 4; ++nt) {
      int n = wid * 64 + nt * 16 + l15;
#pragma unroll
      for (int mt = 0; mt < 2; ++mt) {
        int row = i0 + mt * 16 + quad * 4;
#pragma unroll
        for (int r = 0; r < 4; ++r)
          out[(size_t)(b * L_ + row + r) * 256 + n] = acc[mt][nt][r];
      }
    }
  }
}

// ---------------------------------------------------------------------------
extern "C" void kernel_launch(void* const* d_in, const int* in_sizes, int n_in,
                              void* d_out, int out_size, void* d_ws, size_t ws_size,
                              hipStream_t stream) {
  (void)in_sizes; (void)n_in; (void)out_size; (void)ws_size;

  const float* query = (const float*)d_in[0];
  const float* key   = (const float*)d_in[1];
  const float* value = (const float*)d_in[2];
  const float* Wq = (const float*)d_in[3];
  const float* bq = (const float*)d_in[4];
  const float* Wk = (const float*)d_in[5];
  const float* bk = (const float*)d_in[6];
  const float* Wv = (const float*)d_in[7];
  const float* bv = (const float*)d_in[8];
  const float* Wo = (const float*)d_in[9];
  const float* bo = (const float*)d_in[10];

  float* out    = (float*)d_out;                 // [B, L, 256] f32
  float* attn_f = out + (size_t)B_ * L_ * D_;    // [B, L, L]   f32

  // ws (~21 MB; ws_size ~544 MB per harness poison fills):
  // bc + 6 split weight mats + qhi/qlo + khi/klo + uT
  char* ws = (char*)d_ws;
  const size_t WSZ = 256 * 256;
  const size_t MSZ = (size_t)B_ * L_ * D_;
  float* bc = (float*)ws;                    // 1 KB (padded to 4 KB)
  bf16* wqThi = (bf16*)(ws + 4096);
  bf16* wqTlo = wqThi + WSZ;
  bf16* wkThi = wqTlo + WSZ;
  bf16* wkTlo = wkThi + WSZ;
  bf16* wcThi = wkTlo + WSZ;
  bf16* wcTlo = wcThi + WSZ;
  bf16* qhi = wcTlo + WSZ;    // 4 MB
  bf16* qlo = qhi + MSZ;      // 4 MB
  bf16* khi = qlo + MSZ;      // 4 MB
  bf16* klo = khi + MSZ;      // 4 MB
  bf16* uT  = klo + MSZ;      // 4 MB, [b][n][L]

  prep_w<<<384, 256, 0, stream>>>(Wq, Wk, Wv, Wo, bv, bo,
                                  wqThi, wqTlo, wkThi, wkTlo, wcThi, wcTlo, bc);
  gemm3<<<dim3(64, 4, 3), 256, 0, stream>>>(query, key, value,
                                            wqThi, wqTlo, wkThi, wkTlo, wcThi, wcTlo,
                                            bq, bk, bc, qhi, qlo, khi, klo, uT);
  attn_fused<<<dim3(L_ / 32, B_), 256, 0, stream>>>(qhi, qlo, khi, klo, uT, attn_f, out);
}

// Round 8
// 263.847 us; speedup vs baseline: 1.1530x; 1.0129x over previous
//
#include <hip/hip_runtime.h>

#define B_ 2
#define L_ 4096
#define D_ 256
#define W_ 128

typedef __bf16 bf16;
typedef __bf16 bf16x8 __attribute__((ext_vector_type(8)));
typedef __bf16 bf16x4 __attribute__((ext_vector_type(4)));
typedef float f32x4 __attribute__((ext_vector_type(4)));

#define MFMA16(a, b, c) __builtin_amdgcn_mfma_f32_16x16x32_bf16((a), (b), (c), 0, 0, 0)

__device__ __forceinline__ int imin(int a, int b) { return a < b ? a : b; }
__device__ __forceinline__ int imax(int a, int b) { return a > b ? a : b; }

// Split 8 consecutive f32 into hi/lo bf16 fragments (hi = rn(x), lo = rn(x-hi)).
__device__ __forceinline__ void split8(const float* p, bf16x8& hi, bf16x8& lo) {
  f32x4 v0 = ((const f32x4*)p)[0], v1 = ((const f32x4*)p)[1];
#pragma unroll
  for (int j = 0; j < 4; ++j) {
    bf16 h0 = (bf16)v0[j]; hi[j] = h0; lo[j] = (bf16)(v0[j] - (float)h0);
    bf16 h1 = (bf16)v1[j]; hi[j + 4] = h1; lo[j + 4] = (bf16)(v1[j] - (float)h1);
  }
}

// ---------------------------------------------------------------------------
// prep_w: 384 blocks x 256 threads.
//   [0,64)    transpose-split Wq     [64,128) transpose-split Wk
//   [128,384) row i of Wc = Wv@Wo (f32, 8-way ILP), stored transposed-split;
//             block i==0 also computes bc = bv@Wo + bo.
// ---------------------------------------------------------------------------
__global__ __launch_bounds__(256) void prep_w(
    const float* __restrict__ Wq, const float* __restrict__ Wk,
    const float* __restrict__ Wv, const float* __restrict__ Wo,
    const float* __restrict__ bv, const float* __restrict__ bo,
    bf16* __restrict__ wqThi, bf16* __restrict__ wqTlo,
    bf16* __restrict__ wkThi, bf16* __restrict__ wkTlo,
    bf16* __restrict__ wcThi, bf16* __restrict__ wcTlo,
    float* __restrict__ bc) {
  int blk = blockIdx.x;
  if (blk < 128) {
    int m = blk >> 6;  // 0: Wq, 1: Wk
    int t = blk & 63;
    int bx = t & 7, by = t >> 3;
    const float* src = m ? Wk : Wq;
    bf16* dh = m ? wkThi : wqThi;
    bf16* dl = m ? wkTlo : wqTlo;
    __shared__ float s[32][33];
    int c = threadIdx.x & 31, r0 = threadIdx.x >> 5;
    int br = by * 32, bcc = bx * 32;
    for (int rr = r0; rr < 32; rr += 8) s[rr][c] = src[(br + rr) * 256 + bcc + c];
    __syncthreads();
    for (int rr = r0; rr < 32; rr += 8) {
      float v = s[c][rr];
      bf16 h = (bf16)v;
      dh[(bcc + rr) * 256 + br + c] = h;
      dl[(bcc + rr) * 256 + br + c] = (bf16)(v - (float)h);
    }
    return;
  }
  int i = blk - 128, j = threadIdx.x;
  float acc[8] = {};
  for (int k0 = 0; k0 < 256; k0 += 8) {
#pragma unroll
    for (int t = 0; t < 8; ++t)
      acc[t] = fmaf(Wv[i * 256 + k0 + t], Wo[(k0 + t) * 256 + j], acc[t]);
  }
  float s = ((acc[0] + acc[1]) + (acc[2] + acc[3])) + ((acc[4] + acc[5]) + (acc[6] + acc[7]));
  bf16 h = (bf16)s;
  wcThi[j * 256 + i] = h;  // wcT[n=j][k=i]
  wcTlo[j * 256 + i] = (bf16)(s - (float)h);
  if (i == 0) {
    float bacc[8] = {};
    for (int k0 = 0; k0 < 256; k0 += 8) {
#pragma unroll
      for (int t = 0; t < 8; ++t)
        bacc[t] = fmaf(bv[k0 + t], Wo[(k0 + t) * 256 + j], bacc[t]);
    }
    bc[j] = ((bacc[0] + bacc[1]) + (bacc[2] + bacc[3])) +
            ((bacc[4] + bacc[5]) + (bacc[6] + bacc[7])) + bo[j];
  }
}

// ---------------------------------------------------------------------------
// gemm3: three independent projections in one launch, XCD-swizzled so the 4
// N-blocks sharing one A row-block have linear ids spaced 8 apart (same XCD
// under round-robin dispatch) -> A re-reads hit that XCD's L2.
// y=0: q (split store)  y=1: k (split store)  y=2: u (bf16, [b][n][L])
// grid (256, 3), block 256 (4 waves; wave = 32 rows x 64 cols)
// ---------------------------------------------------------------------------
__global__ __launch_bounds__(256) void gemm3(
    const float* __restrict__ query, const float* __restrict__ key,
    const float* __restrict__ value,
    const bf16* __restrict__ wqThi, const bf16* __restrict__ wqTlo,
    const bf16* __restrict__ wkThi, const bf16* __restrict__ wkTlo,
    const bf16* __restrict__ wcThi, const bf16* __restrict__ wcTlo,
    const float* __restrict__ bq, const float* __restrict__ bk,
    const float* __restrict__ bc,
    bf16* __restrict__ qhi, bf16* __restrict__ qlo,
    bf16* __restrict__ khi, bf16* __restrict__ klo, bf16* __restrict__ uT) {
  const float* A; const bf16 *WThi, *WTlo; const float* bias;
  bf16 *Chi, *Clo; int storeT;
  switch (blockIdx.y) {
    case 0: A = query; WThi = wqThi; WTlo = wqTlo; bias = bq; Chi = qhi; Clo = qlo; storeT = 0; break;
    case 1: A = key;   WThi = wkThi; WTlo = wkTlo; bias = bk; Chi = khi; Clo = klo; storeT = 0; break;
    default: A = value; WThi = wcThi; WTlo = wcTlo; bias = bc; Chi = uT; Clo = uT; storeT = 1; break;
  }
  int tid = threadIdx.x;
  int wid = tid >> 6, lane = tid & 63, l15 = lane & 15, quad = lane >> 4;
  int id = blockIdx.x;                       // 0..255
  int mb = (id & 7) | ((id >> 5) << 3);      // 0..63
  int nbi = (id >> 3) & 3;                   // 0..3
  int mw = mb * 128 + wid * 32;
  int nb = nbi * 64;

  f32x4 acc[2][4] = {};
  const float* a0p = A + (size_t)(mw + l15) * 256 + quad * 8;
  const float* a1p = a0p + 16 * 256;

#pragma unroll
  for (int ks = 0; ks < 8; ++ks) {
    int kb = ks * 32;
    bf16x8 a0h, a0l, a1h, a1l;
    split8(a0p + kb, a0h, a0l);
    split8(a1p + kb, a1h, a1l);
#pragma unroll
    for (int nt = 0; nt < 4; ++nt) {
      size_t woff = (size_t)(nb + nt * 16 + l15) * 256 + kb + quad * 8;
      bf16x8 wh = *(const bf16x8*)(WThi + woff);
      bf16x8 wl = *(const bf16x8*)(WTlo + woff);
      acc[0][nt] = MFMA16(a0l, wh, MFMA16(a0h, wl, MFMA16(a0h, wh, acc[0][nt])));
      acc[1][nt] = MFMA16(a1l, wh, MFMA16(a1h, wl, MFMA16(a1h, wh, acc[1][nt])));
    }
  }

#pragma unroll
  for (int nt = 0; nt < 4; ++nt) {
    int n = nb + nt * 16 + l15;
    float bvv = bias[n];
#pragma unroll
    for (int mt = 0; mt < 2; ++mt) {
      int mbase = mw + mt * 16 + quad * 4;
      if (!storeT) {
#pragma unroll
        for (int r = 0; r < 4; ++r) {
          float v = acc[mt][nt][r] + bvv;
          bf16 h = (bf16)v;
          Chi[(size_t)(mbase + r) * 256 + n] = h;
          Clo[(size_t)(mbase + r) * 256 + n] = (bf16)(v - (float)h);
        }
      } else {
        int b = mbase >> 12;
        int l = mbase & (L_ - 1);
        bf16x4 pv;
#pragma unroll
        for (int r = 0; r < 4; ++r) pv[r] = (bf16)(acc[mt][nt][r] + bvv);
        *(bf16x4*)(Chi + ((size_t)b * 256 + n) * L_ + l) = pv;
      }
    }
  }
}

// ---------------------------------------------------------------------------
// attn_fused: one block = 16 query rows. grid (256, B) = 512 blocks = 2/CU.
// Phase parity stagger ((bx^by)&1): even blocks write zero-slots first (store
// drain overlaps co-resident odd block's MFMA), odd blocks write them last.
// ---------------------------------------------------------------------------
__global__ __launch_bounds__(256, 2) void attn_fused(
    const bf16* __restrict__ qhi, const bf16* __restrict__ qlo,
    const bf16* __restrict__ khi, const bf16* __restrict__ klo,
    const bf16* __restrict__ uT, float* __restrict__ attn,
    float* __restrict__ out) {
  const int tid = threadIdx.x;
  const int bx = blockIdx.x, b = blockIdx.y;
  const int i0 = bx * 16;
  int wid = tid >> 6, lane = tid & 63, l15 = lane & 15, quad = lane >> 4;

  int jlo = imax(0, i0 - W_);
  int jhi = imin(L_, i0 + 16 + W_);
  int span = jhi - jlo;                // multiple of 16, <= 272
  int spanp = (span + 31) & ~31;       // <= 288
  int nch = span >> 4;                 // 16-col chunks

  __shared__ float sc[16][292];

  bool early = ((bx ^ b) & 1) == 0;

  // zero-slot writer: all 16B slots fully outside the band
  auto write_zeros = [&]() {
    for (int idx = tid; idx < 16 * 1024; idx += 256) {
      int rr = idx >> 10, s = idx & 1023;
      int ig = i0 + rr;
      int slo = imax(0, ig - W_) >> 2;
      int shi = imin(L_ - 1, ig + W_) >> 2;
      if (s < slo || s > shi) {
        f32x4 z = {0.f, 0.f, 0.f, 0.f};
        __builtin_nontemporal_store(z, (f32x4*)(attn + (size_t)(b * L_ + ig) * L_ + s * 4));
      }
    }
  };
  if (early) write_zeros();

  // ---- 1) band scores, 3-MFMA split product; q fragments hoisted
  bf16x8 qh[8], ql[8];
  {
    size_t q0 = (size_t)(b * L_ + i0 + l15) * 256 + quad * 8;
#pragma unroll
    for (int ks = 0; ks < 8; ++ks) {
      qh[ks] = *(const bf16x8*)(qhi + q0 + ks * 32);
      ql[ks] = *(const bf16x8*)(qlo + q0 + ks * 32);
    }
  }
  for (int c = wid; c < nch; c += 4) {
    int jb = jlo + c * 16;
    size_t k0 = (size_t)(b * L_ + jb + l15) * 256 + quad * 8;
    f32x4 acc = {};
#pragma unroll
    for (int ks = 0; ks < 8; ++ks) {
      bf16x8 kh = *(const bf16x8*)(khi + k0 + ks * 32);
      bf16x8 kl = *(const bf16x8*)(klo + k0 + ks * 32);
      acc = MFMA16(ql[ks], kh, MFMA16(qh[ks], kl, MFMA16(qh[ks], kh, acc)));
    }
#pragma unroll
    for (int r = 0; r < 4; ++r) sc[quad * 4 + r][c * 16 + l15] = acc[r];
  }
  __syncthreads();

  // ---- 2) masked softmax, 16 threads per row; also zero sc pad cols for PV
  {
    int r = tid >> 4, s = tid & 15;
    int ig = i0 + r;
    float m = -1e30f;
    for (int jj = s; jj < span; jj += 16) {
      int jg = jlo + jj;
      if (jg >= ig - W_ && jg <= ig + W_) m = fmaxf(m, sc[r][jj]);
    }
#pragma unroll
    for (int off = 1; off < 16; off <<= 1) m = fmaxf(m, __shfl_xor(m, off, 16));
    float sum = 0.f;
    for (int jj = s; jj < span; jj += 16) {
      int jg = jlo + jj;
      bool inb = (jg >= ig - W_ && jg <= ig + W_);
      float p = inb ? __expf(sc[r][jj] - m) : 0.f;
      sc[r][jj] = p;
      sum += p;
    }
#pragma unroll
    for (int off = 1; off < 16; off <<= 1) sum += __shfl_xor(sum, off, 16);
    float inv = 1.f / sum;
    for (int jj = s; jj < span; jj += 16) sc[r][jj] *= inv;
    int pc = span + s;
    if (pc < spanp) sc[r][pc] = 0.f;
  }
  __syncthreads();

  // ---- 3) band write (issued before PV so stores drain under MFMA)
  for (int rr = 0; rr < 16; ++rr) {
    int ig = i0 + rr;
    int slo = imax(0, ig - W_) >> 2;
    int shi = imin(L_ - 1, ig + W_) >> 2;
    float* arow = attn + (size_t)(b * L_ + ig) * L_;
    for (int s = slo + tid; s <= shi; s += 256) {
      int j0 = s * 4;
      f32x4 v;
#pragma unroll
      for (int e = 0; e < 4; ++e) {
        int jg = j0 + e;
        bool inb = (jg >= ig - W_) && (jg <= ig + W_);
        v[e] = inb ? sc[rr][imax(jg - jlo, 0)] : 0.f;
      }
      __builtin_nontemporal_store(v, (f32x4*)(arow + j0));
    }
  }

  // ---- 4) PV: out = P @ u  (wave w handles cols [w*64, w*64+64))
  {
    f32x4 acc[4] = {};
    for (int kc = 0; kc < (spanp >> 5); ++kc) {
      int kb = kc * 32 + quad * 8;
      bf16x8 a;
      {
        const f32x4* pp = (const f32x4*)&sc[l15][kb];
        f32x4 lo = pp[0], hi = pp[1];
#pragma unroll
        for (int j = 0; j < 4; ++j) { a[j] = (bf16)lo[j]; a[j + 4] = (bf16)hi[j]; }
      }
#pragma unroll
      for (int nt = 0; nt < 4; ++nt) {
        const bf16* up = uT + ((size_t)b * 256 + wid * 64 + nt * 16 + l15) * L_ + jlo + kb;
        acc[nt] = MFMA16(a, *(const bf16x8*)up, acc[nt]);
      }
    }
#pragma unroll
    for (int nt = 0; nt < 4; ++nt) {
      int n = wid * 64 + nt * 16 + l15;
      int row = i0 + quad * 4;
#pragma unroll
      for (int r = 0; r < 4; ++r)
        out[(size_t)(b * L_ + row + r) * 256 + n] = acc[nt][r];
    }
  }

  if (!early) write_zeros();
}

// ---------------------------------------------------------------------------
extern "C" void kernel_launch(void* const* d_in, const int* in_sizes, int n_in,
                              void* d_out, int out_size, void* d_ws, size_t ws_size,
                              hipStream_t stream) {
  (void)in_sizes; (void)n_in; (void)out_size; (void)ws_size;

  const float* query = (const float*)d_in[0];
  const float* key   = (const float*)d_in[1];
  const float* value = (const float*)d_in[2];
  const float* Wq = (const float*)d_in[3];
  const float* bq = (const float*)d_in[4];
  const float* Wk = (const float*)d_in[5];
  const float* bk = (const float*)d_in[6];
  const float* Wv = (const float*)d_in[7];
  const float* bv = (const float*)d_in[8];
  const float* Wo = (const float*)d_in[9];
  const float* bo = (const float*)d_in[10];

  float* out    = (float*)d_out;                 // [B, L, 256] f32
  float* attn_f = out + (size_t)B_ * L_ * D_;    // [B, L, L]   f32

  // ws (~21 MB of ~544 MB): bc + 6 split weight mats + q/k hi/lo + uT (+pad)
  char* ws = (char*)d_ws;
  const size_t WSZ = 256 * 256;
  const size_t MSZ = (size_t)B_ * L_ * D_;
  float* bc = (float*)ws;                    // 1 KB (padded to 4 KB)
  bf16* wqThi = (bf16*)(ws + 4096);
  bf16* wqTlo = wqThi + WSZ;
  bf16* wkThi = wqTlo + WSZ;
  bf16* wkTlo = wkThi + WSZ;
  bf16* wcThi = wkTlo + WSZ;
  bf16* wcTlo = wcThi + WSZ;
  bf16* qhi = wcTlo + WSZ;    // 4 MB
  bf16* qlo = qhi + MSZ;      // 4 MB
  bf16* khi = qlo + MSZ;      // 4 MB
  bf16* klo = khi + MSZ;      // 4 MB
  bf16* uT  = klo + MSZ;      // 4 MB, [b][n][L]; PV may read <=64 elems past
                              // the end (prob=0, poison decodes finite) — pad
                              // exists inside the 544 MB ws.

  prep_w<<<384, 256, 0, stream>>>(Wq, Wk, Wv, Wo, bv, bo,
                                  wqThi, wqTlo, wkThi, wkTlo, wcThi, wcTlo, bc);
  gemm3<<<dim3(256, 3), 256, 0, stream>>>(query, key, value,
                                          wqThi, wqTlo, wkThi, wkTlo, wcThi, wcTlo,
                                          bq, bk, bc, qhi, qlo, khi, klo, uT);
  attn_fused<<<dim3(L_ / 16, B_), 256, 0, stream>>>(qhi, qlo, khi, klo, uT, attn_f, out);
}